// Round 3
// baseline (99.261 us; speedup 1.0000x reference)
//
#include <hip/hip_runtime.h>
#include <math.h>

#define BB 256      // batch
#define CC 1024     // channels
#define CC4 (CC/4)  // row length in float4
#define MARGIN 0.5f
#define NTILE 64    // j-tiles (of 4) per row
#define JPT 4       // j's per tile
#define NP  128     // i-pairs

// ---------------------------------------------------------------------------
// Kernel A: mcsq[i,c] = m_counts[i,c]^2 (float).
// One wave per row i. Partner selection via ballot; float4 loads.
// Block 0 also zero-inits the final-reduce accumulator + counter.
// ---------------------------------------------------------------------------
__global__ __launch_bounds__(64) void mcsq_kernel(
    const float* __restrict__ x, const int* __restrict__ targets,
    const int* __restrict__ subs, const int* __restrict__ m_count_p,
    float* __restrict__ mcsq, float* __restrict__ acc,
    unsigned int* __restrict__ cnt_g)
{
    const int i = blockIdx.x;
    const int lane = threadIdx.x;
    if (i == 0 && lane == 0) { *acc = 0.f; *cnt_g = 0u; }
    const int ti = targets[i], si = subs[i];
    int mc = *m_count_p;
    if (mc > 8) mc = 8;

    unsigned long long masks[4];
    #pragma unroll
    for (int q = 0; q < 4; ++q) {
        const int j = q * 64 + lane;
        masks[q] = __ballot(targets[j] == ti && subs[j] == si);
    }
    int idx[8];
    int cnt = 0;
    for (int q = 0; q < 4 && cnt < mc; ++q) {
        unsigned long long m = masks[q];
        while (m && cnt < mc) {
            const int b = __ffsll(m) - 1;
            idx[cnt++] = q * 64 + b;
            m &= m - 1;
        }
    }
    for (int q = 0; q < 4 && cnt < mc; ++q) {   // stable-argsort padding
        unsigned long long m = ~masks[q];
        while (m && cnt < mc) {
            const int b = __ffsll(m) - 1;
            idx[cnt++] = q * 64 + b;
            m &= m - 1;
        }
    }

    const float4* x4 = (const float4*)x;
    float4 xi[4];
    #pragma unroll
    for (int t = 0; t < 4; ++t) xi[t] = x4[(long)i * CC4 + lane + 64 * t];

    float4 c4[4];
    #pragma unroll
    for (int t = 0; t < 4; ++t) c4[t] = make_float4(0.f, 0.f, 0.f, 0.f);

    for (int k = 0; k < cnt; ++k) {
        float4 ad[4];
        float s = 0.f;
        #pragma unroll
        for (int t = 0; t < 4; ++t) {
            const float4 xj = x4[(long)idx[k] * CC4 + lane + 64 * t];
            ad[t].x = fabsf(xi[t].x - xj.x);
            ad[t].y = fabsf(xi[t].y - xj.y);
            ad[t].z = fabsf(xi[t].z - xj.z);
            ad[t].w = fabsf(xi[t].w - xj.w);
            s += ad[t].x + ad[t].y + ad[t].z + ad[t].w;
        }
        #pragma unroll
        for (int off = 32; off > 0; off >>= 1) s += __shfl_xor(s, off, 64);
        const float thr = s * (MARGIN / CC);   // 0.5 * mean
        #pragma unroll
        for (int t = 0; t < 4; ++t) {
            c4[t].x += (ad[t].x < thr) ? 1.f : 0.f;
            c4[t].y += (ad[t].y < thr) ? 1.f : 0.f;
            c4[t].z += (ad[t].z < thr) ? 1.f : 0.f;
            c4[t].w += (ad[t].w < thr) ? 1.f : 0.f;
        }
    }
    float4* m4 = (float4*)mcsq;
    #pragma unroll
    for (int t = 0; t < 4; ++t) {
        float4 o;
        o.x = c4[t].x * c4[t].x;
        o.y = c4[t].y * c4[t].y;
        o.z = c4[t].z * c4[t].z;
        o.w = c4[t].w * c4[t].w;
        m4[(long)i * CC4 + lane + 64 * t] = o;
    }
}

// ---------------------------------------------------------------------------
// Kernel B: TRIANGULAR pair kernel, jt-grouped, 8 waves/block, LDS staging.
// Block = one jt (4 j-rows) x 8 consecutive p's (one wave each). The block
// stages x[j0..j0+3] and mcsq[j0..j0+3] (32 KB) into LDS ONCE; all 8 waves
// read j-data via ds_read_b128. vs R2: staging traffic and block count are
// HALVED (544 blocks, ~all co-resident at 2 blocks/CU by VGPR).
// Blocks per jt = ceil((jt+1)/4) = G+1 where G=jt>>2; cum before jt=4G+R is
// (G+1)(2G+R); total 544. Per-task arithmetic order and output locations are
// identical to R2 -> bit-exact (absmax must stay 0).
// ---------------------------------------------------------------------------
__global__ __launch_bounds__(512) void pair_kernel(
    const float* __restrict__ x, const float* __restrict__ mcsq,
    const int* __restrict__ targets,
    float* __restrict__ pmax, float* __restrict__ pmin,
    float* __restrict__ pmaxT, float* __restrict__ pminT)
{
    const int tid  = threadIdx.x;
    const int lane = tid & 63;
    const int w    = tid >> 6;     // wave in block: selects p (0..7)
    const int b    = blockIdx.x;   // 0..543

    // invert b -> G: 2G(G+1) <= b < 2(G+1)(G+2)
    int G = (int)((sqrtf(1.0f + 2.0f * (float)b) - 1.0f) * 0.5f);
    if (G < 0) G = 0;
    while (G > 0 && 2 * G * (G + 1) > b) --G;
    while (2 * (G + 1) * (G + 2) <= b) ++G;
    const int rem = b - 2 * G * (G + 1);      // 0 .. 4(G+1)-1
    const int R   = rem / (G + 1);            // 0..3
    const int pg  = rem - R * (G + 1);        // 0..G
    const int jt  = 4 * G + R;
    const int p   = pg * 8 + w;
    const bool valid = (p <= 2 * jt + 1);
    const int pe  = valid ? p : 0;
    const int i0  = 2 * pe, i1 = 2 * pe + 1;
    const int j0  = jt * JPT;

    __shared__ float lds[8192];               // [0..4095]=x rows, [4096..]=mcsq rows
    float4* lds4 = (float4*)lds;

    const float4* x4 = (const float4*)x;
    const float4* m4 = (const float4*)mcsq;

    // --- hoist all target scalars (hide s-load latency under staging) ------
    const int t0 = targets[i0], t1 = targets[i1];
    int tj[4];
    #pragma unroll
    for (int q = 0; q < 4; ++q) tj[q] = targets[j0 + q];

    // --- issue i-row loads (per wave) + j-row staging loads (per block) ----
    float4 xi0[4], xi1[4], mi0[4], mi1[4];
    #pragma unroll
    for (int t = 0; t < 4; ++t) {
        const int c4 = lane + 64 * t;
        xi0[t] = x4[(long)i0 * CC4 + c4];
        xi1[t] = x4[(long)i1 * CC4 + c4];
        mi0[t] = m4[(long)i0 * CC4 + c4];
        mi1[t] = m4[(long)i1 * CC4 + c4];
    }
    // 512 threads stage 8 rows x 256 float4 = 2048 float4 (x: rows 0-3,
    // mcsq: rows 4-7). Each thread: 2 x-loads + 2 m-loads.
    float4 stx[2], stm[2];
    #pragma unroll
    for (int q = 0; q < 2; ++q) {
        const int f   = q * 512 + tid;        // 0..1023
        const int row = f >> 8;               // 0..3
        const int col = f & 255;
        stx[q] = x4[(long)(j0 + row) * CC4 + col];
        stm[q] = m4[(long)(j0 + row) * CC4 + col];
    }
    #pragma unroll
    for (int q = 0; q < 2; ++q) {
        lds4[q * 512 + tid]        = stx[q];
        lds4[1024 + q * 512 + tid] = stm[q];
    }
    __syncthreads();

    if (!valid) return;                       // no barriers after this point

    const float4* lx = lds4;                  // x rows: float4 idx row*256 + c4
    const float4* lm = lds4 + 1024;           // mcsq rows

    float max0 = 0.f, max1 = 0.f;
    float min0 = INFINITY, min1 = INFINITY;

    #pragma unroll
    for (int half = 0; half < 2; ++half) {
        const int jal = 2 * half;             // row index within LDS tile
        const int jbl = jal + 1;
        const int ja  = j0 + jal;
        const int jb  = j0 + jbl;
        const int tja = tj[jal], tjb = tj[jbl];

        // --- load x rows for both j's from LDS --------------------------
        float4 xa[4], xb[4];
        #pragma unroll
        for (int t = 0; t < 4; ++t) {
            const int c4 = lane + 64 * t;
            xa[t] = lx[jal * 256 + c4];
            xb[t] = lx[jbl * 256 + c4];
        }

        // --- L1 partial sums, 4 (row, j) combos -------------------------
        float s0a = 0.f, s1a = 0.f, s0b = 0.f, s1b = 0.f;
        #pragma unroll
        for (int t = 0; t < 4; ++t) {
            s0a += fabsf(xi0[t].x - xa[t].x) + fabsf(xi0[t].y - xa[t].y)
                 + fabsf(xi0[t].z - xa[t].z) + fabsf(xi0[t].w - xa[t].w);
            s1a += fabsf(xi1[t].x - xa[t].x) + fabsf(xi1[t].y - xa[t].y)
                 + fabsf(xi1[t].z - xa[t].z) + fabsf(xi1[t].w - xa[t].w);
            s0b += fabsf(xi0[t].x - xb[t].x) + fabsf(xi0[t].y - xb[t].y)
                 + fabsf(xi0[t].z - xb[t].z) + fabsf(xi0[t].w - xb[t].w);
            s1b += fabsf(xi1[t].x - xb[t].x) + fabsf(xi1[t].y - xb[t].y)
                 + fabsf(xi1[t].z - xb[t].z) + fabsf(xi1[t].w - xb[t].w);
        }

        // --- issue mcsq LDS reads; latency covered by the butterfly -----
        float4 maa[4], mab[4];
        #pragma unroll
        for (int t = 0; t < 4; ++t) {
            const int c4 = lane + 64 * t;
            maa[t] = lm[jal * 256 + c4];
            mab[t] = lm[jbl * 256 + c4];
        }

        // --- 4-var butterfly (4 independent chains) ---------------------
        #pragma unroll
        for (int off2 = 32; off2 > 0; off2 >>= 1) {
            s0a += __shfl_xor(s0a, off2, 64);
            s1a += __shfl_xor(s1a, off2, 64);
            s0b += __shfl_xor(s0b, off2, 64);
            s1b += __shfl_xor(s1b, off2, 64);
        }
        const float thr0a = s0a * (MARGIN / CC);
        const float thr1a = s1a * (MARGIN / CC);
        const float thr0b = s0b * (MARGIN / CC);
        const float thr1b = s1b * (MARGIN / CC);

        // --- masked passes for both j's (8 independent accumulators) ----
        float ids0a = 0.f, ids1a = 0.f, md0a = 0.f, md1a = 0.f;
        float ids0b = 0.f, ids1b = 0.f, md0b = 0.f, md1b = 0.f;
        #pragma unroll
        for (int t = 0; t < 4; ++t) {
            #pragma unroll
            for (int u = 0; u < 4; ++u) {
                const float x0v  = (&xi0[t].x)[u];
                const float x1v  = (&xi1[t].x)[u];
                const float m0v  = (&mi0[t].x)[u];
                const float m1v  = (&mi1[t].x)[u];
                const float xav  = (&xa[t].x)[u];
                const float mav  = (&maa[t].x)[u];
                const float xbv  = (&xb[t].x)[u];
                const float mbv  = (&mab[t].x)[u];

                const float d0a = x0v - xav;
                const float q0a = d0a * d0a;
                ids0a += (fabsf(d0a) < thr0a) ? q0a : 0.f;
                md0a  += q0a * m0v * mav;
                const float d1a = x1v - xav;
                const float q1a = d1a * d1a;
                ids1a += (fabsf(d1a) < thr1a) ? q1a : 0.f;
                md1a  += q1a * m1v * mav;

                const float d0b = x0v - xbv;
                const float q0b = d0b * d0b;
                ids0b += (fabsf(d0b) < thr0b) ? q0b : 0.f;
                md0b  += q0b * m0v * mbv;
                const float d1b = x1v - xbv;
                const float q1b = d1b * d1b;
                ids1b += (fabsf(d1b) < thr1b) ? q1b : 0.f;
                md1b  += q1b * m1v * mbv;
            }
        }

        // --- 8-var butterfly (8 independent chains) ---------------------
        #pragma unroll
        for (int off2 = 32; off2 > 0; off2 >>= 1) {
            ids0a += __shfl_xor(ids0a, off2, 64);
            ids1a += __shfl_xor(ids1a, off2, 64);
            md0a  += __shfl_xor(md0a,  off2, 64);
            md1a  += __shfl_xor(md1a,  off2, 64);
            ids0b += __shfl_xor(ids0b, off2, 64);
            ids1b += __shfl_xor(ids1b, off2, 64);
            md0b  += __shfl_xor(md0b,  off2, 64);
            md1b  += __shfl_xor(md1b,  off2, 64);
        }

        // --- epilogue, jA first then jB (same order as before) ----------
        const float mod0a = sqrtf(fmaxf(md0a, 1e-12f));
        const float mod1a = sqrtf(fmaxf(md1a, 1e-12f));
        const float mod0b = sqrtf(fmaxf(md0b, 1e-12f));
        const float mod1b = sqrtf(fmaxf(md1b, 1e-12f));
        max0 = fmaxf(fmaxf(max0, mod0a), mod0b);
        max1 = fmaxf(fmaxf(max1, mod1a), mod1b);

        float id0a = sqrtf(fmaxf(ids0a, 1e-12f));
        float id1a = sqrtf(fmaxf(ids1a, 1e-12f));
        float id0b = sqrtf(fmaxf(ids0b, 1e-12f));
        float id1b = sqrtf(fmaxf(ids1b, 1e-12f));

        if (tja != t0) min0 = fminf(min0, id0a); else id0a = INFINITY;
        if (tja != t1) min1 = fminf(min1, id1a); else id1a = INFINITY;
        if (tjb != t0) min0 = fminf(min0, id0b); else id0b = INFINITY;
        if (tjb != t1) min1 = fminf(min1, id1b); else id1b = INFINITY;

        if (lane == 0) {                       // j-side (transposed) partials
            pmaxT[ja * NP + p] = fmaxf(mod0a, mod1a);
            pminT[ja * NP + p] = fminf(id0a, id1a);
            pmaxT[jb * NP + p] = fmaxf(mod0b, mod1b);
            pminT[jb * NP + p] = fminf(id0b, id1b);
        }
    }

    if (lane == 0) {                           // i-side partials
        pmax[i0 * NTILE + jt] = max0;
        pmax[i1 * NTILE + jt] = max1;
        pmin[i0 * NTILE + jt] = min0;
        pmin[i1 * NTILE + jt] = min1;
    }
}

// ---------------------------------------------------------------------------
// Kernel C: parallel final reduce. One wave per row: <=3 guarded loads per
// lane, 6-step max/min butterfly, atomicAdd of per_row/BB; last block
// publishes the total to d_out. Valid slots: i-side jt in [i/4, 64),
// transposed p < 2*(i/4)+2 — poisoned slots never read.
// ---------------------------------------------------------------------------
__global__ __launch_bounds__(64) void final_kernel(
    const float* __restrict__ pmax, const float* __restrict__ pmin,
    const float* __restrict__ pmaxT, const float* __restrict__ pminT,
    float* __restrict__ acc, unsigned int* __restrict__ cnt_g,
    float* __restrict__ out)
{
    const int i = blockIdx.x;       // row
    const int lane = threadIdx.x;
    const int s = i >> 2;
    float mx = 0.f, mn = INFINITY;
    const int t = s + lane;
    if (t < NTILE) {
        mx = fmaxf(mx, pmax[i * NTILE + t]);
        mn = fminf(mn, pmin[i * NTILE + t]);
    }
    const int pv = 2 * s + 2;
    if (lane < pv) {
        mx = fmaxf(mx, pmaxT[i * NP + lane]);
        mn = fminf(mn, pminT[i * NP + lane]);
    }
    if (lane + 64 < pv) {
        mx = fmaxf(mx, pmaxT[i * NP + lane + 64]);
        mn = fminf(mn, pminT[i * NP + lane + 64]);
    }
    #pragma unroll
    for (int off = 32; off > 0; off >>= 1) {
        mx = fmaxf(mx, __shfl_xor(mx, off, 64));
        mn = fminf(mn, __shfl_xor(mn, off, 64));
    }
    if (lane == 0) {
        const float per = fmaxf(mx * 10.f - mn, 0.f);
        atomicAdd(acc, per * (1.0f / BB));
        __threadfence();
        const unsigned int old = atomicAdd(cnt_g, 1u);
        if (old == BB - 1) {
            __threadfence();
            out[0] = atomicAdd(acc, 0.0f);   // device-coherent read-back
        }
    }
}

extern "C" void kernel_launch(void* const* d_in, const int* in_sizes, int n_in,
                              void* d_out, int out_size, void* d_ws, size_t ws_size,
                              hipStream_t stream)
{
    const float* x       = (const float*)d_in[0];
    const int*   targets = (const int*)d_in[1];
    const int*   subs    = (const int*)d_in[2];
    const int*   m_count = (const int*)d_in[3];
    float* out  = (float*)d_out;

    float* mcsq  = (float*)d_ws;                  // BB*CC floats = 1 MB
    float* pmax  = mcsq  + (long)BB * CC;         // BB*NTILE
    float* pmin  = pmax  + BB * NTILE;            // BB*NTILE
    float* pmaxT = pmin  + BB * NTILE;            // BB*NP
    float* pminT = pmaxT + BB * NP;               // BB*NP
    float* acc   = pminT + BB * NP;               // 1
    unsigned int* cnt_g = (unsigned int*)(acc + 1);

    mcsq_kernel <<<BB,   64, 0, stream>>>(x, targets, subs, m_count, mcsq, acc, cnt_g);
    pair_kernel <<<544,  512, 0, stream>>>(x, mcsq, targets, pmax, pmin, pmaxT, pminT);
    final_kernel<<<BB,   64, 0, stream>>>(pmax, pmin, pmaxT, pminT, acc, cnt_g, out);
}

// Round 4
// 89.042 us; speedup vs baseline: 1.1148x; 1.1148x over previous
//
#include <hip/hip_runtime.h>
#include <math.h>

#define BB 256      // batch
#define CC 1024     // channels
#define CC4 (CC/4)  // row length in float4
#define MARGIN 0.5f
#define NTILE 64    // j-tiles (of 4) per row
#define JPT 4       // j's per tile

// ---------------------------------------------------------------------------
// Kernel A: mcsq[i,c] = m_counts[i,c]^2 (float).
// One wave per row i. Partner selection via ballot; float4 loads.
// Block 0 also zero-inits the final-reduce accumulator + counter.
// ---------------------------------------------------------------------------
__global__ __launch_bounds__(64) void mcsq_kernel(
    const float* __restrict__ x, const int* __restrict__ targets,
    const int* __restrict__ subs, const int* __restrict__ m_count_p,
    float* __restrict__ mcsq, float* __restrict__ acc,
    unsigned int* __restrict__ cnt_g)
{
    const int i = blockIdx.x;
    const int lane = threadIdx.x;
    if (i == 0 && lane == 0) { *acc = 0.f; *cnt_g = 0u; }
    const int ti = targets[i], si = subs[i];
    int mc = *m_count_p;
    if (mc > 8) mc = 8;

    unsigned long long masks[4];
    #pragma unroll
    for (int q = 0; q < 4; ++q) {
        const int j = q * 64 + lane;
        masks[q] = __ballot(targets[j] == ti && subs[j] == si);
    }
    int idx[8];
    int cnt = 0;
    for (int q = 0; q < 4 && cnt < mc; ++q) {
        unsigned long long m = masks[q];
        while (m && cnt < mc) {
            const int b = __ffsll(m) - 1;
            idx[cnt++] = q * 64 + b;
            m &= m - 1;
        }
    }
    for (int q = 0; q < 4 && cnt < mc; ++q) {   // stable-argsort padding
        unsigned long long m = ~masks[q];
        while (m && cnt < mc) {
            const int b = __ffsll(m) - 1;
            idx[cnt++] = q * 64 + b;
            m &= m - 1;
        }
    }

    const float4* x4 = (const float4*)x;
    float4 xi[4];
    #pragma unroll
    for (int t = 0; t < 4; ++t) xi[t] = x4[(long)i * CC4 + lane + 64 * t];

    float4 c4[4];
    #pragma unroll
    for (int t = 0; t < 4; ++t) c4[t] = make_float4(0.f, 0.f, 0.f, 0.f);

    for (int k = 0; k < cnt; ++k) {
        float4 ad[4];
        float s = 0.f;
        #pragma unroll
        for (int t = 0; t < 4; ++t) {
            const float4 xj = x4[(long)idx[k] * CC4 + lane + 64 * t];
            ad[t].x = fabsf(xi[t].x - xj.x);
            ad[t].y = fabsf(xi[t].y - xj.y);
            ad[t].z = fabsf(xi[t].z - xj.z);
            ad[t].w = fabsf(xi[t].w - xj.w);
            s += ad[t].x + ad[t].y + ad[t].z + ad[t].w;
        }
        #pragma unroll
        for (int off = 32; off > 0; off >>= 1) s += __shfl_xor(s, off, 64);
        const float thr = s * (MARGIN / CC);   // 0.5 * mean
        #pragma unroll
        for (int t = 0; t < 4; ++t) {
            c4[t].x += (ad[t].x < thr) ? 1.f : 0.f;
            c4[t].y += (ad[t].y < thr) ? 1.f : 0.f;
            c4[t].z += (ad[t].z < thr) ? 1.f : 0.f;
            c4[t].w += (ad[t].w < thr) ? 1.f : 0.f;
        }
    }
    float4* m4 = (float4*)mcsq;
    #pragma unroll
    for (int t = 0; t < 4; ++t) {
        float4 o;
        o.x = c4[t].x * c4[t].x;
        o.y = c4[t].y * c4[t].y;
        o.z = c4[t].z * c4[t].z;
        o.w = c4[t].w * c4[t].w;
        m4[(long)i * CC4 + lane + 64 * t] = o;
    }
}

// ---------------------------------------------------------------------------
// Kernel B: TRIANGULAR pair kernel, LOW-PRESSURE form: one i-row per wave,
// one j at a time. Live set per wave: xi/mi (32 VGPR) + xa/maa (32) + accs
// => ~90 VGPR demand, under the 128 cap -> no spills / no load-use
// serialization (the R1-R3 versions demanded ~140+ with 116 allocated).
// Block = (ig, jt) with ig <= jt: 4 waves (i = ig*4+w), LDS-stages the 4
// j-rows (x + mcsq, 32 KB) once. 2080 uniform blocks x 4 waves = 8320 waves
// (2x TLP of R1). Every unordered pair computed at least once; diagonal-tile
// duplicates are harmless (max/min idempotent). Per-(i,j) arithmetic order
// is IDENTICAL to R1-R3 -> bit-exact (absmax must stay 0).
// i-side partial: pmax/pmin[i][jt] (jt >= i>>2). j-side (transposed)
// partial: pmaxT/pminT[j][i], written for i < 4*(j>>2)+4.
// ---------------------------------------------------------------------------
__global__ __launch_bounds__(256) void pair_kernel(
    const float* __restrict__ x, const float* __restrict__ mcsq,
    const int* __restrict__ targets,
    float* __restrict__ pmax, float* __restrict__ pmin,
    float* __restrict__ pmaxT, float* __restrict__ pminT)
{
    const int tid  = threadIdx.x;
    const int lane = tid & 63;
    const int w    = tid >> 6;     // wave in block -> i within group
    const int b    = blockIdx.x;   // 0..2079

    // decode b -> (jt, ig): b = jt(jt+1)/2 + ig, ig in [0, jt]
    int jt = (int)((sqrtf(8.0f * (float)b + 1.0f) - 1.0f) * 0.5f);
    if (jt < 0) jt = 0;
    if (jt > 63) jt = 63;
    while (jt > 0 && (jt * (jt + 1)) / 2 > b) --jt;
    while (((jt + 1) * (jt + 2)) / 2 <= b) ++jt;
    const int ig = b - (jt * (jt + 1)) / 2;   // 0..jt
    const int i  = ig * 4 + w;                // wave's i-row
    const int j0 = jt * JPT;

    __shared__ float lds[8192];               // [0..4095]=x rows, [4096..]=mcsq rows
    float4* lds4 = (float4*)lds;

    const float4* x4 = (const float4*)x;
    const float4* m4 = (const float4*)mcsq;

    // --- hoist scalars ------------------------------------------------------
    const int ti = targets[i];
    int tj[4];
    #pragma unroll
    for (int q = 0; q < 4; ++q) tj[q] = targets[j0 + q];

    // --- i-row loads (per wave, registers) ---------------------------------
    float4 xi[4], mi[4];
    #pragma unroll
    for (int t = 0; t < 4; ++t) {
        const int c4 = lane + 64 * t;
        xi[t] = x4[(long)i * CC4 + c4];
        mi[t] = m4[(long)i * CC4 + c4];
    }

    // --- stage 4 j-rows of x and mcsq into LDS (256 thr x 8 float4) --------
    {
        float4 st[8];
        #pragma unroll
        for (int q = 0; q < 4; ++q) {
            st[q]     = x4[(long)(j0 + q) * CC4 + tid];
            st[4 + q] = m4[(long)(j0 + q) * CC4 + tid];
        }
        #pragma unroll
        for (int q = 0; q < 8; ++q) lds4[q * 256 + tid] = st[q];
    }
    __syncthreads();

    const float4* lx = lds4;                  // x rows: row*256 + c4
    const float4* lm = lds4 + 1024;           // mcsq rows

    float mx = 0.f, mn = INFINITY;

    #pragma unroll
    for (int jj = 0; jj < JPT; ++jj) {
        const int j = j0 + jj;

        // --- x row from LDS + L1 partial sum ----------------------------
        float4 xa[4];
        float s = 0.f;
        #pragma unroll
        for (int t = 0; t < 4; ++t) {
            xa[t] = lx[jj * 256 + lane + 64 * t];
            s += fabsf(xi[t].x - xa[t].x) + fabsf(xi[t].y - xa[t].y)
               + fabsf(xi[t].z - xa[t].z) + fabsf(xi[t].w - xa[t].w);
        }

        // --- issue mcsq LDS reads; latency covered by butterfly ---------
        float4 ma[4];
        #pragma unroll
        for (int t = 0; t < 4; ++t) ma[t] = lm[jj * 256 + lane + 64 * t];

        #pragma unroll
        for (int off = 32; off > 0; off >>= 1) s += __shfl_xor(s, off, 64);
        const float thr = s * (MARGIN / CC);

        // --- masked pass ------------------------------------------------
        float ids = 0.f, md = 0.f;
        #pragma unroll
        for (int t = 0; t < 4; ++t) {
            #pragma unroll
            for (int u = 0; u < 4; ++u) {
                const float xiv = (&xi[t].x)[u];
                const float miv = (&mi[t].x)[u];
                const float xav = (&xa[t].x)[u];
                const float mav = (&ma[t].x)[u];
                const float d = xiv - xav;
                const float q = d * d;
                ids += (fabsf(d) < thr) ? q : 0.f;
                md  += q * miv * mav;
            }
        }
        #pragma unroll
        for (int off = 32; off > 0; off >>= 1) {
            ids += __shfl_xor(ids, off, 64);
            md  += __shfl_xor(md,  off, 64);
        }

        // --- epilogue ---------------------------------------------------
        const float mod = sqrtf(fmaxf(md, 1e-12f));
        float idv = sqrtf(fmaxf(ids, 1e-12f));
        mx = fmaxf(mx, mod);
        if (tj[jj] != ti) mn = fminf(mn, idv); else idv = INFINITY;

        if (lane == 0) {                      // j-side (transposed) partial
            pmaxT[j * BB + i] = mod;
            pminT[j * BB + i] = idv;
        }
    }

    if (lane == 0) {                          // i-side partials
        pmax[i * NTILE + jt] = mx;
        pmin[i * NTILE + jt] = mn;
    }
}

// ---------------------------------------------------------------------------
// Kernel C: parallel final reduce. One wave per row: i-side jt in [i>>2, 64)
// (1 guarded load), transposed i' < 4*(i>>2)+4 (4 guarded loads); 6-step
// max/min butterfly; atomicAdd of per_row/BB; last block publishes to d_out.
// Poisoned (never-written) slots are never read.
// ---------------------------------------------------------------------------
__global__ __launch_bounds__(64) void final_kernel(
    const float* __restrict__ pmax, const float* __restrict__ pmin,
    const float* __restrict__ pmaxT, const float* __restrict__ pminT,
    float* __restrict__ acc, unsigned int* __restrict__ cnt_g,
    float* __restrict__ out)
{
    const int i = blockIdx.x;       // row
    const int lane = threadIdx.x;
    const int s = i >> 2;
    float mx = 0.f, mn = INFINITY;
    const int t = s + lane;
    if (t < NTILE) {
        mx = fmaxf(mx, pmax[i * NTILE + t]);
        mn = fminf(mn, pmin[i * NTILE + t]);
    }
    const int pv = 4 * s + 4;       // transposed valid i' count
    #pragma unroll
    for (int q = 0; q < 4; ++q) {
        const int c = lane + 64 * q;
        if (c < pv) {
            mx = fmaxf(mx, pmaxT[i * BB + c]);
            mn = fminf(mn, pminT[i * BB + c]);
        }
    }
    #pragma unroll
    for (int off = 32; off > 0; off >>= 1) {
        mx = fmaxf(mx, __shfl_xor(mx, off, 64));
        mn = fminf(mn, __shfl_xor(mn, off, 64));
    }
    if (lane == 0) {
        const float per = fmaxf(mx * 10.f - mn, 0.f);
        atomicAdd(acc, per * (1.0f / BB));
        __threadfence();
        const unsigned int old = atomicAdd(cnt_g, 1u);
        if (old == BB - 1) {
            __threadfence();
            out[0] = atomicAdd(acc, 0.0f);   // device-coherent read-back
        }
    }
}

extern "C" void kernel_launch(void* const* d_in, const int* in_sizes, int n_in,
                              void* d_out, int out_size, void* d_ws, size_t ws_size,
                              hipStream_t stream)
{
    const float* x       = (const float*)d_in[0];
    const int*   targets = (const int*)d_in[1];
    const int*   subs    = (const int*)d_in[2];
    const int*   m_count = (const int*)d_in[3];
    float* out  = (float*)d_out;

    float* mcsq  = (float*)d_ws;                  // BB*CC floats = 1 MB
    float* pmax  = mcsq  + (long)BB * CC;         // BB*NTILE
    float* pmin  = pmax  + BB * NTILE;            // BB*NTILE
    float* pmaxT = pmin  + BB * NTILE;            // BB*BB
    float* pminT = pmaxT + BB * BB;               // BB*BB
    float* acc   = pminT + BB * BB;               // 1
    unsigned int* cnt_g = (unsigned int*)(acc + 1);

    mcsq_kernel <<<BB,   64, 0, stream>>>(x, targets, subs, m_count, mcsq, acc, cnt_g);
    pair_kernel <<<2080, 256, 0, stream>>>(x, mcsq, targets, pmax, pmin, pmaxT, pminT);
    final_kernel<<<BB,   64, 0, stream>>>(pmax, pmin, pmaxT, pminT, acc, cnt_g, out);
}